// Round 7
// baseline (396.501 us; speedup 1.0000x reference)
//
#include <hip/hip_runtime.h>
#include <hip/hip_cooperative_groups.h>
#include <hip/hip_fp16.h>

namespace cg = cooperative_groups;

#define EPS 0.1f
#define SINK_ITERS 50
#define KSCALE_LN 9.0109133472f   /* 13*ln2 : K scaled by 2^13 into f16 normal range */

typedef _Float16 f16;
typedef _Float16 f16x4 __attribute__((ext_vector_type(4)));
typedef _Float16 f16x8 __attribute__((ext_vector_type(8)));
typedef float f32x4 __attribute__((ext_vector_type(4)));

#define PIN_U4(v) asm volatile("" : "+v"(v.x), "+v"(v.y), "+v"(v.z), "+v"(v.w))

__device__ __forceinline__ float wave_red_sum(float v) {
    #pragma unroll
    for (int o = 32; o; o >>= 1) v += __shfl_xor(v, o, 64);
    return v;
}
__device__ __forceinline__ int wave_red_sum_i(int v) {
    #pragma unroll
    for (int o = 32; o; o >>= 1) v += __shfl_xor(v, o, 64);
    return v;
}

// LDS union across phases (per-block; phases separated by grid.sync / __syncthreads)
union __align__(16) SM {
    struct { f16 Ai[64 * 40]; f16 Bj[64 * 40]; } g;             // gemm stage (10240 B)
    struct { f16 U[4 * 272]; float ZP[256][4]; float CW[4][3]; } s; // sinkhorn
    struct { float a[8]; float b[8]; } r;                        // pre reductions
    struct { int redc[8]; int bin[2]; int tot; } m;              // median
    float red[8];                                                // prep reductions
};

__device__ __forceinline__ int med_bin(float v) {
    int b = (int)(v * 4096.f);
    if (v < (float)b * (1.f / 4096.f)) b--;
    else if (v >= (float)(b + 1) * (1.f / 4096.f)) b++;
    if (b < 0) b = 0;
    if (b > 8191) b = 8191;
    return b;
}

// ---- one 64x64 Gram tile over a 256-wide k slab (8 chunks of 32), 8 waves ----
__device__ __forceinline__ void gemm_unit(const uint4* __restrict__ X, int lda8,
                                          int i0, int j0, int kb8_0,
                                          float* __restrict__ out, SM& sm, int t) {
    int lane = t & 63, wv = t >> 6, m16 = lane & 15, quad = lane >> 4;
    int rr = (t & 255) >> 2, kk = t & 3;
    int rbase = (t < 256) ? i0 : j0;
    f16* stg = (t < 256) ? sm.g.Ai : sm.g.Bj;
    f32x4 a0 = {0.f, 0.f, 0.f, 0.f}, a1 = {0.f, 0.f, 0.f, 0.f};
    for (int ch = 0; ch < 8; ch++) {
        uint4 v = X[(size_t)(rbase + rr) * lda8 + kb8_0 + ch * 4 + kk];
        __syncthreads();
        *(uint4*)&stg[rr * 40 + kk * 8] = v;
        __syncthreads();
        f16x8 a  = *(const f16x8*)&sm.g.Ai[((wv & 3) * 16 + m16) * 40 + quad * 8];
        f16x8 b0 = *(const f16x8*)&sm.g.Bj[((wv >> 2) * 32 + m16) * 40 + quad * 8];
        f16x8 b1 = *(const f16x8*)&sm.g.Bj[((wv >> 2) * 32 + 16 + m16) * 40 + quad * 8];
        a0 = __builtin_amdgcn_mfma_f32_16x16x32_f16(a, b0, a0, 0, 0, 0);
        a1 = __builtin_amdgcn_mfma_f32_16x16x32_f16(a, b1, a1, 0, 0, 0);
    }
    int orow = i0 + (wv & 3) * 16 + quad * 4;
    int ocol = j0 + (wv >> 2) * 32 + m16;
    #pragma unroll
    for (int reg = 0; reg < 4; reg++) {
        out[(orow + reg) * 256 + ocol] = a0[reg];
        out[(orow + reg) * 256 + ocol + 16] = a1[reg];
    }
}

// ---- prep row helpers ----
__device__ __forceinline__ void prep_a_row(int row, int t, SM& sm,
                                           const float* __restrict__ part2,
                                           const float* __restrict__ Do,
                                           const float* __restrict__ lsl,
                                           float* __restrict__ Pl, float* __restrict__ ELl,
                                           f16* __restrict__ Kh) {
    float x = lsl[0];
    float sp = (x > 20.f) ? x : log1pf(__expf(x));
    float sgl = sp + 1e-6f;
    float i2l = 1.f / (2.f * sgl * sgl);
    float slv = 0.f, dov = 0.f;
    if (t < 256) {
        int e = row * 256 + t;
        float dl = fmaxf(1.f - part2[e], 0.f);
        slv = (row == t) ? 0.f : __expf(-dl * dl * i2l);
        dov = Do[e];
    }
    float ws = wave_red_sum(slv);
    if ((t & 63) == 0) sm.red[t >> 6] = ws;
    __syncthreads();
    float tot = sm.red[0] + sm.red[1] + sm.red[2] + sm.red[3];
    if (t < 256) {
        int e = row * 256 + t;
        float pl = slv / fmaxf(tot, 1e-8f);
        Pl[e] = pl;
        ELl[e] = EPS * __logf(fmaxf(pl, 1e-8f));
        float kv = __expf(-dov * (1.f / EPS) + KSCALE_LN);
        Kh[(((row >> 3) * 256 + t) << 3) + (row & 7)] = (f16)kv;
    }
    __syncthreads();
}

__device__ __forceinline__ void prep_b_row(int row, int t, SM& sm,
                                           const float* __restrict__ Do,
                                           const float* __restrict__ acc,
                                           float* __restrict__ Po, float* __restrict__ ELo) {
    float sg = acc[4];
    if (sg == 0.f) sg = 1e-6f;
    float i2o = 1.f / (2.f * sg * sg);
    float sov = 0.f;
    if (t < 256) {
        float dov = Do[row * 256 + t];
        sov = (row == t) ? 0.f : __expf(-dov * dov * i2o);
    }
    float ws = wave_red_sum(sov);
    if ((t & 63) == 0) sm.red[t >> 6] = ws;
    __syncthreads();
    float tot = sm.red[0] + sm.red[1] + sm.red[2] + sm.red[3];
    if (t < 256) {
        int e = row * 256 + t;
        float po = sov / fmaxf(tot, 1e-8f);
        Po[e] = po;
        ELo[e] = EPS * __logf(fmaxf(po, 1e-8f));
    }
    __syncthreads();
}

// ---- exact median (block 0 only): global 8192-bin hist + in-register bisection ----
__device__ void median_phase(const float* __restrict__ Do, const int* __restrict__ hist,
                             float* __restrict__ acc, SM& sm, int t) {
    int lane = t & 63, wv = t >> 6;
    unsigned r[128];
    #pragma unroll
    for (int i = 0; i < 128; i++) r[i] = __float_as_uint(Do[t + i * 512]);
    int base = t * 16;
    int s16 = 0;
    for (int j = 0; j < 16; j++) s16 += hist[base + j];
    int inc = s16;
    #pragma unroll
    for (int o = 1; o < 64; o <<= 1) {
        int vv = __shfl_up(inc, o, 64);
        if (lane >= o) inc += vv;
    }
    if (lane == 63) sm.m.redc[wv] = inc;
    __syncthreads();
    int woff = 0;
    for (int i = 0; i < wv; i++) woff += sm.m.redc[i];
    int excl = woff + inc - s16;
    for (int sel = 0; sel < 2; sel++) {
        int k = 32767 + sel;
        if (excl <= k && k < excl + s16) {
            int cum = excl, bfound = 8191;
            bool found = false;
            for (int j = 0; j < 16; j++) {
                int hc = hist[base + j];
                if (!found) {
                    if (cum + hc > k) { bfound = base + j; found = true; }
                    else cum += hc;
                }
            }
            sm.m.bin[sel] = bfound;
        }
    }
    __syncthreads();
    unsigned res[2];
    for (int sel = 0; sel < 2; sel++) {
        int k = 32767 + sel;
        int bb = sm.m.bin[sel];
        unsigned lo = __float_as_uint((float)bb * (1.f / 4096.f));
        unsigned hi = __float_as_uint((float)(bb + 1) * (1.f / 4096.f));
        while (hi - lo > 1u) {
            unsigned mid = (lo + hi) >> 1;
            int c = 0;
            #pragma unroll
            for (int i = 0; i < 128; i++) c += (r[i] < mid) ? 1 : 0;
            c = wave_red_sum_i(c);
            if (lane == 0) sm.m.redc[wv] = c;
            __syncthreads();
            if (t == 0) {
                int tot = 0;
                for (int i = 0; i < 8; i++) tot += sm.m.redc[i];
                sm.m.tot = tot;
            }
            __syncthreads();
            if (sm.m.tot <= k) lo = mid; else hi = mid;
        }
        res[sel] = lo;
    }
    if (t == 0)
        acc[4] = 0.5f * (__uint_as_float(res[0]) + __uint_as_float(res[1]));
}

// ================= fused cooperative kernel: 256 blocks x 512 threads =================
__global__ __launch_bounds__(512, 2) void k_fused(const float4* __restrict__ xo4,
                                                  const float4* __restrict__ xr4,
                                                  const float4* __restrict__ z4,
                                                  const float* __restrict__ lsl,
                                                  const float* __restrict__ lvr,
                                                  const float* __restrict__ lvt,
                                                  float* __restrict__ out,
                                                  float* __restrict__ ws) {
    cg::grid_group grid = cg::this_grid();
    __shared__ SM sm;
    const int b = blockIdx.x, t = threadIdx.x;
    const int lane = t & 63, wv = t >> 6, m16 = lane & 15, quad = lane >> 4;

    // ws layout
    float* acc = ws;                         // [0..2] ot, [3] recon, [4] sigma
    int* hist = (int*)(ws + 64);             // 8192 bins (memset to 0 with acc)
    f16* xh = (f16*)(ws + 64 + 8192);        // 256x4096 f16
    f16* zh = xh + 1048576;                  // 256x256 f16
    float* Do = (float*)(zh + 65536);
    float* Po = Do + 65536;
    float* Pl = Po + 65536;
    float* ELo = Pl + 65536;
    float* ELl = ELo + 65536;
    f16* Kh = (f16*)(ELl + 65536);           // 65536 f16
    float* part = (float*)(Kh + 65536);      // 16 x 65536
    float* part2 = part + 16 * 65536;        // 65536

    // ---------- P0: recon + normalize (block b owns xo-row b, xr-row b, z-row b) ----------
    {
        if (t < 64) {
            float4 vz = z4[(size_t)b * 64 + t];
            float sz = vz.x * vz.x + vz.y * vz.y + vz.z * vz.z + vz.w * vz.w;
            sz = wave_red_sum(sz);
            float rnz = 1.f / sqrtf(fmaxf(sz, 1e-8f));
            f16x4 h;
            h[0] = (f16)(vz.x * rnz); h[1] = (f16)(vz.y * rnz);
            h[2] = (f16)(vz.z * rnz); h[3] = (f16)(vz.w * rnz);
            *(f16x4*)&zh[(size_t)b * 256 + t * 4] = h;
        }
        size_t ro = (size_t)b * 1024;
        float4 v0 = xo4[ro + t], v1 = xo4[ro + t + 512];
        float4 r0 = xr4[ro + t], r1 = xr4[ro + t + 512];
        float sq = v0.x * v0.x + v0.y * v0.y + v0.z * v0.z + v0.w * v0.w
                 + v1.x * v1.x + v1.y * v1.y + v1.z * v1.z + v1.w * v1.w;
        float d0 = r0.x - v0.x, d1 = r0.y - v0.y, d2 = r0.z - v0.z, d3 = r0.w - v0.w;
        float e0 = r1.x - v1.x, e1 = r1.y - v1.y, e2 = r1.z - v1.z, e3 = r1.w - v1.w;
        float rs = d0 * d0 + d1 * d1 + d2 * d2 + d3 * d3
                 + e0 * e0 + e1 * e1 + e2 * e2 + e3 * e3;
        float wq = wave_red_sum(sq), wr = wave_red_sum(rs);
        if (lane == 0) { sm.r.a[wv] = wq; sm.r.b[wv] = wr; }
        __syncthreads();
        float tq = 0.f, tr = 0.f;
        #pragma unroll
        for (int i = 0; i < 8; i++) { tq += sm.r.a[i]; tr += sm.r.b[i]; }
        if (t == 0) atomicAdd(acc + 3, tr);
        float rn = 1.f / sqrtf(fmaxf(tq, 1e-8f));
        f16x4 h0, h1;
        h0[0] = (f16)(v0.x * rn); h0[1] = (f16)(v0.y * rn);
        h0[2] = (f16)(v0.z * rn); h0[3] = (f16)(v0.w * rn);
        h1[0] = (f16)(v1.x * rn); h1[1] = (f16)(v1.y * rn);
        h1[2] = (f16)(v1.z * rn); h1[3] = (f16)(v1.w * rn);
        *(f16x4*)&xh[(size_t)b * 4096 + t * 4] = h0;
        *(f16x4*)&xh[(size_t)b * 4096 + 2048 + t * 4] = h1;
    }
    grid.sync();

    // ---------- P1: Gram GEMMs (f16 MFMA). 256 big units; blocks 240..255 also small ----------
    {
        int tile = b >> 4, slab = b & 15;
        gemm_unit((const uint4*)xh, 512, (tile >> 2) * 64, (tile & 3) * 64,
                  slab * 32, part + (size_t)slab * 65536, sm, t);
        if (b >= 240) {
            int tl = b - 240;
            gemm_unit((const uint4*)zh, 32, (tl >> 2) * 64, (tl & 3) * 64, 0, part2, sm, t);
        }
    }
    grid.sync();

    // ---------- P2: Do = clip(1 - sum slabs) + global histogram ----------
    if (t < 256) {
        int e = b * 256 + t;
        float s = 0.f;
        for (int sl = 0; sl < 16; sl++) s += part[(size_t)sl * 65536 + e];
        float dv = fmaxf(1.f - s, 0.f);
        Do[e] = dv;
        atomicAdd(&hist[med_bin(dv)], 1);
    }
    grid.sync();

    // ---------- P3: block0 median || blocks 1..255 prep-a (Pl, ELl, Kh) ----------
    if (b == 0) {
        median_phase(Do, hist, acc, sm, t);
    } else {
        prep_a_row(b - 1, t, sm, part2, Do, lsl, Pl, ELl, Kh);
        if (b == 255) prep_a_row(255, t, sm, part2, Do, lsl, Pl, ELl, Kh);
    }
    grid.sync();

    // ---------- P4: prep-b (Po, ELo) ----------
    prep_b_row(b, t, sm, Do, acc, Po, ELo);
    grid.sync();

    // ---------- P5: Sinkhorn, P=3 problems per block, waves 0-3 compute ----------
    {
        const uint4* Kq = (const uint4*)Kh;
        uint4 bf[4][8];
        float ela[3] = {}, elb[3] = {};
        const float* pa[3]; const float* pb[3];
        pa[0] = pa[1] = pa[2] = Po; pb[0] = pb[1] = pb[2] = Po;
        if (t < 256) {
            #pragma unroll
            for (int st = 0; st < 4; st++)
                #pragma unroll
                for (int kc = 0; kc < 8; kc++)
                    bf[st][kc] = Kq[(kc * 4 + quad) * 256 + wv * 64 + st * 16 + m16];
            #pragma unroll
            for (int st = 0; st < 4; st++)
                #pragma unroll
                for (int kc = 0; kc < 8; kc++) PIN_U4(bf[st][kc]);
            #pragma unroll
            for (int p = 0; p < 3; p++) {
                int rr = b * 3 + p, s = rr >> 8, ii = rr & 255;
                const float* ea = (s == 1 ? ELl : ELo) + ii * 256;
                const float* eb = (s == 2 ? ELo : ELl) + ii * 256;
                ela[p] = ea[t] + EPS * KSCALE_LN;
                elb[p] = eb[t] + EPS * KSCALE_LN;
                pa[p] = (s == 1 ? Pl : Po) + ii * 256;
                pb[p] = (s == 2 ? Po : Pl) + ii * 256;
            }
        }
        if (t < 136)
            *(uint4*)&sm.s.U[t * 8] =
                make_uint4(0x3C003C00u, 0x3C003C00u, 0x3C003C00u, 0x3C003C00u);
        __syncthreads();

        float fv[3] = {}, gv[3] = {};
        for (int it = 0; it < 2 * SINK_ITERS; it++) {
            if (t < 256) {
                f32x4 a0 = {0.f,0.f,0.f,0.f}, a1 = {0.f,0.f,0.f,0.f};
                f32x4 a2 = {0.f,0.f,0.f,0.f}, a3 = {0.f,0.f,0.f,0.f};
                #pragma unroll
                for (int kc = 0; kc < 8; kc++) {
                    f16x8 a = *(const f16x8*)&sm.s.U[(m16 & 3) * 272 + kc * 32 + quad * 8];
                    a0 = __builtin_amdgcn_mfma_f32_16x16x32_f16(a, __builtin_bit_cast(f16x8, bf[0][kc]), a0, 0, 0, 0);
                    a1 = __builtin_amdgcn_mfma_f32_16x16x32_f16(a, __builtin_bit_cast(f16x8, bf[1][kc]), a1, 0, 0, 0);
                    a2 = __builtin_amdgcn_mfma_f32_16x16x32_f16(a, __builtin_bit_cast(f16x8, bf[2][kc]), a2, 0, 0, 0);
                    a3 = __builtin_amdgcn_mfma_f32_16x16x32_f16(a, __builtin_bit_cast(f16x8, bf[3][kc]), a3, 0, 0, 0);
                }
                if (quad == 0) {
                    *(f32x4*)&sm.s.ZP[wv * 64 + m16][0] = a0;
                    *(f32x4*)&sm.s.ZP[wv * 64 + 16 + m16][0] = a1;
                    *(f32x4*)&sm.s.ZP[wv * 64 + 32 + m16][0] = a2;
                    *(f32x4*)&sm.s.ZP[wv * 64 + 48 + m16][0] = a3;
                }
            }
            __syncthreads();
            if (t < 256) {
                f32x4 zz = *(const f32x4*)&sm.s.ZP[t][0];
                bool fstep = (it & 1);
                #pragma unroll
                for (int p = 0; p < 3; p++) {
                    float el = fstep ? ela[p] : elb[p];
                    float d = el - EPS * __logf(zz[p]);
                    if (fstep) fv[p] = d; else gv[p] = d;
                    sm.s.U[p * 272 + t] = (f16)__expf(d);
                }
            }
            __syncthreads();
        }

        float cs[3] = {};
        if (t < 256) {
            #pragma unroll
            for (int p = 0; p < 3; p++)
                cs[p] = pa[p][t] * fv[p] + pb[p][t] * gv[p];
        }
        #pragma unroll
        for (int p = 0; p < 3; p++) {
            float v = wave_red_sum(cs[p]);
            if (lane == 0 && wv < 4) sm.s.CW[wv][p] = v;
        }
        __syncthreads();
        if (t < 3) {
            float sv = sm.s.CW[0][t] + sm.s.CW[1][t] + sm.s.CW[2][t] + sm.s.CW[3][t];
            atomicAdd(&acc[(b * 3 + t) >> 8], sv);
        }
    }
    grid.sync();

    // ---------- P6: finalize ----------
    if (b == 0 && t == 0) {
        float recon = acc[3] * (1.f / (256.f * 4096.f));
        float ot0 = acc[0] * (1.f / 256.f);
        float ot1 = acc[1] * (1.f / 256.f);
        float ot2 = acc[2] * (1.f / 256.f);
        float topo = ot0 - 0.5f * ot1 - 0.5f * ot2;
        topo = topo > 0.f ? topo : 0.f;
        float a = lvr[0], c = lvt[0];
        out[0] = 0.5f * __expf(-a) * recon + 0.5f * a +
                 0.5f * __expf(-c) * topo + 0.5f * c;
        out[1] = recon;
        out[2] = topo;
    }
}

extern "C" void kernel_launch(void* const* d_in, const int* in_sizes, int n_in,
                              void* d_out, int out_size, void* d_ws, size_t ws_size,
                              hipStream_t stream) {
    const float4* xo4 = (const float4*)d_in[0];
    const float4* xr4 = (const float4*)d_in[1];
    const float4* z4  = (const float4*)d_in[2];
    const float* lsl = (const float*)d_in[3];
    const float* lvr = (const float*)d_in[4];
    const float* lvt = (const float*)d_in[5];
    float* out = (float*)d_out;
    float* ws = (float*)d_ws;

    // zero acc[64] + hist[8192]
    hipMemsetAsync(ws, 0, (64 + 8192) * sizeof(float), stream);

    void* kargs[] = {(void*)&xo4, (void*)&xr4, (void*)&z4, (void*)&lsl,
                     (void*)&lvr, (void*)&lvt, (void*)&out, (void*)&ws};
    hipLaunchCooperativeKernel((void*)k_fused, dim3(256), dim3(512), kargs, 0, stream);
}

// Round 8
// 391.118 us; speedup vs baseline: 1.0138x; 1.0138x over previous
//
#include <hip/hip_runtime.h>
#include <hip/hip_cooperative_groups.h>
#include <hip/hip_fp16.h>

namespace cg = cooperative_groups;

#define EPS 0.1f
#define SINK_ITERS 50
#define KSCALE_LN 9.0109133472f   /* 13*ln2 : K scaled by 2^13 into f16 normal range */

typedef _Float16 f16;
typedef _Float16 f16x4 __attribute__((ext_vector_type(4)));
typedef _Float16 f16x8 __attribute__((ext_vector_type(8)));
typedef float f32x4 __attribute__((ext_vector_type(4)));

#define PIN_U4(v) asm volatile("" : "+v"(v.x), "+v"(v.y), "+v"(v.z), "+v"(v.w))

__device__ __forceinline__ float wave_red_sum(float v) {
    #pragma unroll
    for (int o = 32; o; o >>= 1) v += __shfl_xor(v, o, 64);
    return v;
}
__device__ __forceinline__ int wave_red_sum_i(int v) {
    #pragma unroll
    for (int o = 32; o; o >>= 1) v += __shfl_xor(v, o, 64);
    return v;
}

// LDS union across phases (per-block; phases separated by grid.sync / __syncthreads)
union __align__(16) SM {
    struct { f16 Ai[64 * 40]; f16 Bj[64 * 40]; } g;             // gemm stage (10240 B)
    struct { f16 U[4 * 272]; float ZP[256][4]; float CW[4][3]; } s; // sinkhorn
    struct { float a[8]; float b[8]; } r;                        // pre reductions
    struct { int redc[8]; int bin[2]; int tot; } m;              // median
    float red[8];                                                // prep reductions
};

__device__ __forceinline__ int med_bin(float v) {
    int b = (int)(v * 4096.f);
    if (v < (float)b * (1.f / 4096.f)) b--;
    else if (v >= (float)(b + 1) * (1.f / 4096.f)) b++;
    if (b < 0) b = 0;
    if (b > 8191) b = 8191;
    return b;
}

// ---- one 64x64 Gram tile over a 256-wide k slab (8 chunks of 32), 8 waves ----
__device__ __forceinline__ void gemm_unit(const uint4* __restrict__ X, int lda8,
                                          int i0, int j0, int kb8_0,
                                          float* __restrict__ out, SM& sm, int t) {
    int lane = t & 63, wv = t >> 6, m16 = lane & 15, quad = lane >> 4;
    int rr = (t & 255) >> 2, kk = t & 3;
    int rbase = (t < 256) ? i0 : j0;
    f16* stg = (t < 256) ? sm.g.Ai : sm.g.Bj;
    f32x4 a0 = {0.f, 0.f, 0.f, 0.f}, a1 = {0.f, 0.f, 0.f, 0.f};
    for (int ch = 0; ch < 8; ch++) {
        uint4 v = X[(size_t)(rbase + rr) * lda8 + kb8_0 + ch * 4 + kk];
        __syncthreads();
        *(uint4*)&stg[rr * 40 + kk * 8] = v;
        __syncthreads();
        f16x8 a  = *(const f16x8*)&sm.g.Ai[((wv & 3) * 16 + m16) * 40 + quad * 8];
        f16x8 b0 = *(const f16x8*)&sm.g.Bj[((wv >> 2) * 32 + m16) * 40 + quad * 8];
        f16x8 b1 = *(const f16x8*)&sm.g.Bj[((wv >> 2) * 32 + 16 + m16) * 40 + quad * 8];
        a0 = __builtin_amdgcn_mfma_f32_16x16x32_f16(a, b0, a0, 0, 0, 0);
        a1 = __builtin_amdgcn_mfma_f32_16x16x32_f16(a, b1, a1, 0, 0, 0);
    }
    int orow = i0 + (wv & 3) * 16 + quad * 4;
    int ocol = j0 + (wv >> 2) * 32 + m16;
    #pragma unroll
    for (int reg = 0; reg < 4; reg++) {
        out[(orow + reg) * 256 + ocol] = a0[reg];
        out[(orow + reg) * 256 + ocol + 16] = a1[reg];
    }
}

// ---- prep row helpers ----
__device__ __forceinline__ void prep_a_row(int row, int t, SM& sm,
                                           const float* __restrict__ part2,
                                           const float* __restrict__ Do,
                                           const float* __restrict__ lsl,
                                           float* __restrict__ Pl, float* __restrict__ ELl,
                                           f16* __restrict__ Kh) {
    float x = lsl[0];
    float sp = (x > 20.f) ? x : log1pf(__expf(x));
    float sgl = sp + 1e-6f;
    float i2l = 1.f / (2.f * sgl * sgl);
    float slv = 0.f, dov = 0.f;
    if (t < 256) {
        int e = row * 256 + t;
        float dl = fmaxf(1.f - part2[e], 0.f);
        slv = (row == t) ? 0.f : __expf(-dl * dl * i2l);
        dov = Do[e];
    }
    float ws = wave_red_sum(slv);
    if ((t & 63) == 0) sm.red[t >> 6] = ws;
    __syncthreads();
    float tot = sm.red[0] + sm.red[1] + sm.red[2] + sm.red[3];
    if (t < 256) {
        int e = row * 256 + t;
        float pl = slv / fmaxf(tot, 1e-8f);
        Pl[e] = pl;
        ELl[e] = EPS * __logf(fmaxf(pl, 1e-8f));
        float kv = __expf(-dov * (1.f / EPS) + KSCALE_LN);
        Kh[(((row >> 3) * 256 + t) << 3) + (row & 7)] = (f16)kv;
    }
    __syncthreads();
}

__device__ __forceinline__ void prep_b_row(int row, int t, SM& sm,
                                           const float* __restrict__ Do,
                                           const float* __restrict__ acc,
                                           float* __restrict__ Po, float* __restrict__ ELo) {
    float sg = acc[4];
    if (sg == 0.f) sg = 1e-6f;
    float i2o = 1.f / (2.f * sg * sg);
    float sov = 0.f;
    if (t < 256) {
        float dov = Do[row * 256 + t];
        sov = (row == t) ? 0.f : __expf(-dov * dov * i2o);
    }
    float ws = wave_red_sum(sov);
    if ((t & 63) == 0) sm.red[t >> 6] = ws;
    __syncthreads();
    float tot = sm.red[0] + sm.red[1] + sm.red[2] + sm.red[3];
    if (t < 256) {
        int e = row * 256 + t;
        float po = sov / fmaxf(tot, 1e-8f);
        Po[e] = po;
        ELo[e] = EPS * __logf(fmaxf(po, 1e-8f));
    }
    __syncthreads();
}

// ---- exact median (block 0 only): global 8192-bin hist + in-register bisection ----
__device__ void median_phase(const float* __restrict__ Do, const int* __restrict__ hist,
                             float* __restrict__ acc, SM& sm, int t) {
    int lane = t & 63, wv = t >> 6;
    unsigned r[128];
    #pragma unroll
    for (int i = 0; i < 128; i++) r[i] = __float_as_uint(Do[t + i * 512]);
    int base = t * 16;
    int s16 = 0;
    for (int j = 0; j < 16; j++) s16 += hist[base + j];
    int inc = s16;
    #pragma unroll
    for (int o = 1; o < 64; o <<= 1) {
        int vv = __shfl_up(inc, o, 64);
        if (lane >= o) inc += vv;
    }
    if (lane == 63) sm.m.redc[wv] = inc;
    __syncthreads();
    int woff = 0;
    for (int i = 0; i < wv; i++) woff += sm.m.redc[i];
    int excl = woff + inc - s16;
    for (int sel = 0; sel < 2; sel++) {
        int k = 32767 + sel;
        if (excl <= k && k < excl + s16) {
            int cum = excl, bfound = 8191;
            bool found = false;
            for (int j = 0; j < 16; j++) {
                int hc = hist[base + j];
                if (!found) {
                    if (cum + hc > k) { bfound = base + j; found = true; }
                    else cum += hc;
                }
            }
            sm.m.bin[sel] = bfound;
        }
    }
    __syncthreads();
    unsigned res[2];
    for (int sel = 0; sel < 2; sel++) {
        int k = 32767 + sel;
        int bb = sm.m.bin[sel];
        unsigned lo = __float_as_uint((float)bb * (1.f / 4096.f));
        unsigned hi = __float_as_uint((float)(bb + 1) * (1.f / 4096.f));
        while (hi - lo > 1u) {
            unsigned mid = (lo + hi) >> 1;
            int c = 0;
            #pragma unroll
            for (int i = 0; i < 128; i++) c += (r[i] < mid) ? 1 : 0;
            c = wave_red_sum_i(c);
            if (lane == 0) sm.m.redc[wv] = c;
            __syncthreads();
            if (t == 0) {
                int tot = 0;
                for (int i = 0; i < 8; i++) tot += sm.m.redc[i];
                sm.m.tot = tot;
            }
            __syncthreads();
            if (sm.m.tot <= k) lo = mid; else hi = mid;
        }
        res[sel] = lo;
    }
    if (t == 0)
        acc[4] = 0.5f * (__uint_as_float(res[0]) + __uint_as_float(res[1]));
}

// ================= fused cooperative kernel: 256 blocks x 512 threads =================
// __launch_bounds__(512, 1): grid is 1 block/CU anyway (256 blocks / 256 CUs);
// the ",2" in R7 capped VGPRs at ~128 and spilled P5's 128-VGPR K fragment ->
// 100-step global-reload disaster. At ",1" the cap is 256 and K stays resident.
__global__ __launch_bounds__(512, 1) void k_fused(const float4* __restrict__ xo4,
                                                  const float4* __restrict__ xr4,
                                                  const float4* __restrict__ z4,
                                                  const float* __restrict__ lsl,
                                                  const float* __restrict__ lvr,
                                                  const float* __restrict__ lvt,
                                                  float* __restrict__ out,
                                                  float* __restrict__ ws) {
    cg::grid_group grid = cg::this_grid();
    __shared__ SM sm;
    const int b = blockIdx.x, t = threadIdx.x;
    const int lane = t & 63, wv = t >> 6, m16 = lane & 15, quad = lane >> 4;

    // ws layout
    float* acc = ws;                         // [0..2] ot, [3] recon, [4] sigma
    int* hist = (int*)(ws + 64);             // 8192 bins (memset to 0 with acc)
    f16* xh = (f16*)(ws + 64 + 8192);        // 256x4096 f16
    f16* zh = xh + 1048576;                  // 256x256 f16
    float* Do = (float*)(zh + 65536);
    float* Po = Do + 65536;
    float* Pl = Po + 65536;
    float* ELo = Pl + 65536;
    float* ELl = ELo + 65536;
    f16* Kh = (f16*)(ELl + 65536);           // 65536 f16
    float* part = (float*)(Kh + 65536);      // 16 x 65536
    float* part2 = part + 16 * 65536;        // 65536

    // ---------- P0: recon + normalize (block b owns xo-row b, xr-row b, z-row b) ----------
    {
        if (t < 64) {
            float4 vz = z4[(size_t)b * 64 + t];
            float sz = vz.x * vz.x + vz.y * vz.y + vz.z * vz.z + vz.w * vz.w;
            sz = wave_red_sum(sz);
            float rnz = 1.f / sqrtf(fmaxf(sz, 1e-8f));
            f16x4 h;
            h[0] = (f16)(vz.x * rnz); h[1] = (f16)(vz.y * rnz);
            h[2] = (f16)(vz.z * rnz); h[3] = (f16)(vz.w * rnz);
            *(f16x4*)&zh[(size_t)b * 256 + t * 4] = h;
        }
        size_t ro = (size_t)b * 1024;
        float4 v0 = xo4[ro + t], v1 = xo4[ro + t + 512];
        float4 r0 = xr4[ro + t], r1 = xr4[ro + t + 512];
        float sq = v0.x * v0.x + v0.y * v0.y + v0.z * v0.z + v0.w * v0.w
                 + v1.x * v1.x + v1.y * v1.y + v1.z * v1.z + v1.w * v1.w;
        float d0 = r0.x - v0.x, d1 = r0.y - v0.y, d2 = r0.z - v0.z, d3 = r0.w - v0.w;
        float e0 = r1.x - v1.x, e1 = r1.y - v1.y, e2 = r1.z - v1.z, e3 = r1.w - v1.w;
        float rs = d0 * d0 + d1 * d1 + d2 * d2 + d3 * d3
                 + e0 * e0 + e1 * e1 + e2 * e2 + e3 * e3;
        float wq = wave_red_sum(sq), wr = wave_red_sum(rs);
        if (lane == 0) { sm.r.a[wv] = wq; sm.r.b[wv] = wr; }
        __syncthreads();
        float tq = 0.f, tr = 0.f;
        #pragma unroll
        for (int i = 0; i < 8; i++) { tq += sm.r.a[i]; tr += sm.r.b[i]; }
        if (t == 0) atomicAdd(acc + 3, tr);
        float rn = 1.f / sqrtf(fmaxf(tq, 1e-8f));
        f16x4 h0, h1;
        h0[0] = (f16)(v0.x * rn); h0[1] = (f16)(v0.y * rn);
        h0[2] = (f16)(v0.z * rn); h0[3] = (f16)(v0.w * rn);
        h1[0] = (f16)(v1.x * rn); h1[1] = (f16)(v1.y * rn);
        h1[2] = (f16)(v1.z * rn); h1[3] = (f16)(v1.w * rn);
        *(f16x4*)&xh[(size_t)b * 4096 + t * 4] = h0;
        *(f16x4*)&xh[(size_t)b * 4096 + 2048 + t * 4] = h1;
    }
    grid.sync();

    // ---------- P1: Gram GEMMs (f16 MFMA). 256 big units; blocks 240..255 also small ----------
    {
        int tile = b >> 4, slab = b & 15;
        gemm_unit((const uint4*)xh, 512, (tile >> 2) * 64, (tile & 3) * 64,
                  slab * 32, part + (size_t)slab * 65536, sm, t);
        if (b >= 240) {
            int tl = b - 240;
            gemm_unit((const uint4*)zh, 32, (tl >> 2) * 64, (tl & 3) * 64, 0, part2, sm, t);
        }
    }
    grid.sync();

    // ---------- P2: Do = clip(1 - sum slabs) + global histogram ----------
    if (t < 256) {
        int e = b * 256 + t;
        float s = 0.f;
        for (int sl = 0; sl < 16; sl++) s += part[(size_t)sl * 65536 + e];
        float dv = fmaxf(1.f - s, 0.f);
        Do[e] = dv;
        atomicAdd(&hist[med_bin(dv)], 1);
    }
    grid.sync();

    // ---------- P3: block0 median || blocks 1..255 prep-a (Pl, ELl, Kh) ----------
    if (b == 0) {
        median_phase(Do, hist, acc, sm, t);
    } else {
        prep_a_row(b - 1, t, sm, part2, Do, lsl, Pl, ELl, Kh);
        if (b == 255) prep_a_row(255, t, sm, part2, Do, lsl, Pl, ELl, Kh);
    }
    grid.sync();

    // ---------- P4: prep-b (Po, ELo) ----------
    prep_b_row(b, t, sm, Do, acc, Po, ELo);
    grid.sync();

    // ---------- P5: Sinkhorn, P=3 problems per block, waves 0-3 compute ----------
    {
        const uint4* Kq = (const uint4*)Kh;
        uint4 bf[4][8];
        float ela[3] = {}, elb[3] = {};
        const float* pa[3]; const float* pb[3];
        pa[0] = pa[1] = pa[2] = Po; pb[0] = pb[1] = pb[2] = Po;
        if (t < 256) {
            #pragma unroll
            for (int st = 0; st < 4; st++)
                #pragma unroll
                for (int kc = 0; kc < 8; kc++)
                    bf[st][kc] = Kq[(kc * 4 + quad) * 256 + wv * 64 + st * 16 + m16];
            #pragma unroll
            for (int st = 0; st < 4; st++)
                #pragma unroll
                for (int kc = 0; kc < 8; kc++) PIN_U4(bf[st][kc]);
            #pragma unroll
            for (int p = 0; p < 3; p++) {
                int rr = b * 3 + p, s = rr >> 8, ii = rr & 255;
                const float* ea = (s == 1 ? ELl : ELo) + ii * 256;
                const float* eb = (s == 2 ? ELo : ELl) + ii * 256;
                ela[p] = ea[t] + EPS * KSCALE_LN;
                elb[p] = eb[t] + EPS * KSCALE_LN;
                pa[p] = (s == 1 ? Pl : Po) + ii * 256;
                pb[p] = (s == 2 ? Po : Pl) + ii * 256;
            }
        }
        if (t < 136)
            *(uint4*)&sm.s.U[t * 8] =
                make_uint4(0x3C003C00u, 0x3C003C00u, 0x3C003C00u, 0x3C003C00u);
        __syncthreads();

        float fv[3] = {}, gv[3] = {};
        for (int it = 0; it < 2 * SINK_ITERS; it++) {
            if (t < 256) {
                f32x4 a0 = {0.f,0.f,0.f,0.f}, a1 = {0.f,0.f,0.f,0.f};
                f32x4 a2 = {0.f,0.f,0.f,0.f}, a3 = {0.f,0.f,0.f,0.f};
                #pragma unroll
                for (int kc = 0; kc < 8; kc++) {
                    f16x8 a = *(const f16x8*)&sm.s.U[(m16 & 3) * 272 + kc * 32 + quad * 8];
                    a0 = __builtin_amdgcn_mfma_f32_16x16x32_f16(a, __builtin_bit_cast(f16x8, bf[0][kc]), a0, 0, 0, 0);
                    a1 = __builtin_amdgcn_mfma_f32_16x16x32_f16(a, __builtin_bit_cast(f16x8, bf[1][kc]), a1, 0, 0, 0);
                    a2 = __builtin_amdgcn_mfma_f32_16x16x32_f16(a, __builtin_bit_cast(f16x8, bf[2][kc]), a2, 0, 0, 0);
                    a3 = __builtin_amdgcn_mfma_f32_16x16x32_f16(a, __builtin_bit_cast(f16x8, bf[3][kc]), a3, 0, 0, 0);
                }
                if (quad == 0) {
                    *(f32x4*)&sm.s.ZP[wv * 64 + m16][0] = a0;
                    *(f32x4*)&sm.s.ZP[wv * 64 + 16 + m16][0] = a1;
                    *(f32x4*)&sm.s.ZP[wv * 64 + 32 + m16][0] = a2;
                    *(f32x4*)&sm.s.ZP[wv * 64 + 48 + m16][0] = a3;
                }
            }
            __syncthreads();
            if (t < 256) {
                f32x4 zz = *(const f32x4*)&sm.s.ZP[t][0];
                bool fstep = (it & 1);
                #pragma unroll
                for (int p = 0; p < 3; p++) {
                    float el = fstep ? ela[p] : elb[p];
                    float d = el - EPS * __logf(zz[p]);
                    if (fstep) fv[p] = d; else gv[p] = d;
                    sm.s.U[p * 272 + t] = (f16)__expf(d);
                }
            }
            __syncthreads();
        }

        float cs[3] = {};
        if (t < 256) {
            #pragma unroll
            for (int p = 0; p < 3; p++)
                cs[p] = pa[p][t] * fv[p] + pb[p][t] * gv[p];
        }
        #pragma unroll
        for (int p = 0; p < 3; p++) {
            float v = wave_red_sum(cs[p]);
            if (lane == 0 && wv < 4) sm.s.CW[wv][p] = v;
        }
        __syncthreads();
        if (t < 3) {
            float sv = sm.s.CW[0][t] + sm.s.CW[1][t] + sm.s.CW[2][t] + sm.s.CW[3][t];
            atomicAdd(&acc[(b * 3 + t) >> 8], sv);
        }
    }
    grid.sync();

    // ---------- P6: finalize ----------
    if (b == 0 && t == 0) {
        float recon = acc[3] * (1.f / (256.f * 4096.f));
        float ot0 = acc[0] * (1.f / 256.f);
        float ot1 = acc[1] * (1.f / 256.f);
        float ot2 = acc[2] * (1.f / 256.f);
        float topo = ot0 - 0.5f * ot1 - 0.5f * ot2;
        topo = topo > 0.f ? topo : 0.f;
        float a = lvr[0], c = lvt[0];
        out[0] = 0.5f * __expf(-a) * recon + 0.5f * a +
                 0.5f * __expf(-c) * topo + 0.5f * c;
        out[1] = recon;
        out[2] = topo;
    }
}

extern "C" void kernel_launch(void* const* d_in, const int* in_sizes, int n_in,
                              void* d_out, int out_size, void* d_ws, size_t ws_size,
                              hipStream_t stream) {
    const float4* xo4 = (const float4*)d_in[0];
    const float4* xr4 = (const float4*)d_in[1];
    const float4* z4  = (const float4*)d_in[2];
    const float* lsl = (const float*)d_in[3];
    const float* lvr = (const float*)d_in[4];
    const float* lvt = (const float*)d_in[5];
    float* out = (float*)d_out;
    float* ws = (float*)d_ws;

    // zero acc[64] + hist[8192]
    hipMemsetAsync(ws, 0, (64 + 8192) * sizeof(float), stream);

    void* kargs[] = {(void*)&xo4, (void*)&xr4, (void*)&z4, (void*)&lsl,
                     (void*)&lvr, (void*)&lvt, (void*)&out, (void*)&ws};
    hipLaunchCooperativeKernel((void*)k_fused, dim3(256), dim3(512), kargs, 0, stream);
}

// Round 9
// 360.224 us; speedup vs baseline: 1.1007x; 1.0858x over previous
//
#include <hip/hip_runtime.h>
#include <hip/hip_cooperative_groups.h>
#include <hip/hip_fp16.h>

namespace cg = cooperative_groups;

#define EPS 0.1f
#define SINK_ITERS 50
#define KSCALE_LN 9.0109133472f   /* 13*ln2 : K scaled by 2^13 into f16 normal range */

typedef _Float16 f16;
typedef _Float16 f16x4 __attribute__((ext_vector_type(4)));
typedef _Float16 f16x8 __attribute__((ext_vector_type(8)));
typedef float f32x4 __attribute__((ext_vector_type(4)));

#define PIN_U4(v) asm volatile("" : "+v"(v.x), "+v"(v.y), "+v"(v.z), "+v"(v.w))

__device__ __forceinline__ float wave_red_sum(float v) {
    #pragma unroll
    for (int o = 32; o; o >>= 1) v += __shfl_xor(v, o, 64);
    return v;
}
__device__ __forceinline__ int wave_red_sum_i(int v) {
    #pragma unroll
    for (int o = 32; o; o >>= 1) v += __shfl_xor(v, o, 64);
    return v;
}

// LDS union for the pre kernel
union __align__(16) SM {
    struct { f16 Ai[64 * 40]; f16 Bj[64 * 40]; } g;   // gemm stage (10240 B)
    struct { float a[8]; float b[8]; } r;             // pre reductions
    struct { int redc[8]; int bin[2]; int tot; } m;   // median
    float red[8];                                     // prep reductions
};

__device__ __forceinline__ int med_bin(float v) {
    int b = (int)(v * 4096.f);
    if (v < (float)b * (1.f / 4096.f)) b--;
    else if (v >= (float)(b + 1) * (1.f / 4096.f)) b++;
    if (b < 0) b = 0;
    if (b > 8191) b = 8191;
    return b;
}

// ---- one 64x64 Gram tile over a 256-wide k slab (8 chunks of 32), 8 waves ----
__device__ __forceinline__ void gemm_unit(const uint4* __restrict__ X, int lda8,
                                          int i0, int j0, int kb8_0,
                                          float* __restrict__ out, SM& sm, int t) {
    int lane = t & 63, wv = t >> 6, m16 = lane & 15, quad = lane >> 4;
    int rr = (t & 255) >> 2, kk = t & 3;
    int rbase = (t < 256) ? i0 : j0;
    f16* stg = (t < 256) ? sm.g.Ai : sm.g.Bj;
    f32x4 a0 = {0.f, 0.f, 0.f, 0.f}, a1 = {0.f, 0.f, 0.f, 0.f};
    for (int ch = 0; ch < 8; ch++) {
        uint4 v = X[(size_t)(rbase + rr) * lda8 + kb8_0 + ch * 4 + kk];
        __syncthreads();
        *(uint4*)&stg[rr * 40 + kk * 8] = v;
        __syncthreads();
        f16x8 a  = *(const f16x8*)&sm.g.Ai[((wv & 3) * 16 + m16) * 40 + quad * 8];
        f16x8 b0 = *(const f16x8*)&sm.g.Bj[((wv >> 2) * 32 + m16) * 40 + quad * 8];
        f16x8 b1 = *(const f16x8*)&sm.g.Bj[((wv >> 2) * 32 + 16 + m16) * 40 + quad * 8];
        a0 = __builtin_amdgcn_mfma_f32_16x16x32_f16(a, b0, a0, 0, 0, 0);
        a1 = __builtin_amdgcn_mfma_f32_16x16x32_f16(a, b1, a1, 0, 0, 0);
    }
    int orow = i0 + (wv & 3) * 16 + quad * 4;
    int ocol = j0 + (wv >> 2) * 32 + m16;
    #pragma unroll
    for (int reg = 0; reg < 4; reg++) {
        out[(orow + reg) * 256 + ocol] = a0[reg];
        out[(orow + reg) * 256 + ocol + 16] = a1[reg];
    }
}

// ---- prep row helpers ----
__device__ __forceinline__ void prep_a_row(int row, int t, SM& sm,
                                           const float* __restrict__ part2,
                                           const float* __restrict__ Do,
                                           const float* __restrict__ lsl,
                                           float* __restrict__ Pl, float* __restrict__ ELl,
                                           f16* __restrict__ Kh) {
    float x = lsl[0];
    float sp = (x > 20.f) ? x : log1pf(__expf(x));
    float sgl = sp + 1e-6f;
    float i2l = 1.f / (2.f * sgl * sgl);
    float slv = 0.f, dov = 0.f;
    if (t < 256) {
        int e = row * 256 + t;
        float dl = fmaxf(1.f - part2[e], 0.f);
        slv = (row == t) ? 0.f : __expf(-dl * dl * i2l);
        dov = Do[e];
    }
    float ws = wave_red_sum(slv);
    if ((t & 63) == 0) sm.red[t >> 6] = ws;
    __syncthreads();
    float tot = sm.red[0] + sm.red[1] + sm.red[2] + sm.red[3];
    if (t < 256) {
        int e = row * 256 + t;
        float pl = slv / fmaxf(tot, 1e-8f);
        Pl[e] = pl;
        ELl[e] = EPS * __logf(fmaxf(pl, 1e-8f));
        float kv = __expf(-dov * (1.f / EPS) + KSCALE_LN);
        Kh[(((row >> 3) * 256 + t) << 3) + (row & 7)] = (f16)kv;
    }
    __syncthreads();
}

__device__ __forceinline__ void prep_b_row(int row, int t, SM& sm,
                                           const float* __restrict__ Do,
                                           const float* __restrict__ acc,
                                           float* __restrict__ Po, float* __restrict__ ELo) {
    float sg = acc[4];
    if (sg == 0.f) sg = 1e-6f;
    float i2o = 1.f / (2.f * sg * sg);
    float sov = 0.f;
    if (t < 256) {
        float dov = Do[row * 256 + t];
        sov = (row == t) ? 0.f : __expf(-dov * dov * i2o);
    }
    float ws = wave_red_sum(sov);
    if ((t & 63) == 0) sm.red[t >> 6] = ws;
    __syncthreads();
    float tot = sm.red[0] + sm.red[1] + sm.red[2] + sm.red[3];
    if (t < 256) {
        int e = row * 256 + t;
        float po = sov / fmaxf(tot, 1e-8f);
        Po[e] = po;
        ELo[e] = EPS * __logf(fmaxf(po, 1e-8f));
    }
    __syncthreads();
}

// ---- exact median (block 0 only): global 8192-bin hist + in-register bisection ----
__device__ void median_phase(const float* __restrict__ Do, const int* __restrict__ hist,
                             float* __restrict__ acc, SM& sm, int t) {
    int lane = t & 63, wv = t >> 6;
    unsigned r[128];
    #pragma unroll
    for (int i = 0; i < 128; i++) r[i] = __float_as_uint(Do[t + i * 512]);
    int base = t * 16;
    int s16 = 0;
    for (int j = 0; j < 16; j++) s16 += hist[base + j];
    int inc = s16;
    #pragma unroll
    for (int o = 1; o < 64; o <<= 1) {
        int vv = __shfl_up(inc, o, 64);
        if (lane >= o) inc += vv;
    }
    if (lane == 63) sm.m.redc[wv] = inc;
    __syncthreads();
    int woff = 0;
    for (int i = 0; i < wv; i++) woff += sm.m.redc[i];
    int excl = woff + inc - s16;
    for (int sel = 0; sel < 2; sel++) {
        int k = 32767 + sel;
        if (excl <= k && k < excl + s16) {
            int cum = excl, bfound = 8191;
            bool found = false;
            for (int j = 0; j < 16; j++) {
                int hc = hist[base + j];
                if (!found) {
                    if (cum + hc > k) { bfound = base + j; found = true; }
                    else cum += hc;
                }
            }
            sm.m.bin[sel] = bfound;
        }
    }
    __syncthreads();
    unsigned res[2];
    for (int sel = 0; sel < 2; sel++) {
        int k = 32767 + sel;
        int bb = sm.m.bin[sel];
        unsigned lo = __float_as_uint((float)bb * (1.f / 4096.f));
        unsigned hi = __float_as_uint((float)(bb + 1) * (1.f / 4096.f));
        while (hi - lo > 1u) {
            unsigned mid = (lo + hi) >> 1;
            int c = 0;
            #pragma unroll
            for (int i = 0; i < 128; i++) c += (r[i] < mid) ? 1 : 0;
            c = wave_red_sum_i(c);
            if (lane == 0) sm.m.redc[wv] = c;
            __syncthreads();
            if (t == 0) {
                int tot = 0;
                for (int i = 0; i < 8; i++) tot += sm.m.redc[i];
                sm.m.tot = tot;
            }
            __syncthreads();
            if (sm.m.tot <= k) lo = mid; else hi = mid;
        }
        res[sel] = lo;
    }
    if (t == 0)
        acc[4] = 0.5f * (__uint_as_float(res[0]) + __uint_as_float(res[1]));
}

// ================= cooperative pre kernel: P0..P4 (no sinkhorn) =================
__global__ __launch_bounds__(512, 1) void k_pre_coop(const float4* __restrict__ xo4,
                                                     const float4* __restrict__ xr4,
                                                     const float4* __restrict__ z4,
                                                     const float* __restrict__ lsl,
                                                     float* __restrict__ ws) {
    cg::grid_group grid = cg::this_grid();
    __shared__ SM sm;
    const int b = blockIdx.x, t = threadIdx.x;
    const int lane = t & 63, wv = t >> 6;

    float* acc = ws;
    int* hist = (int*)(ws + 64);
    f16* xh = (f16*)(ws + 64 + 8192);
    f16* zh = xh + 1048576;
    float* Do = (float*)(zh + 65536);
    float* Po = Do + 65536;
    float* Pl = Po + 65536;
    float* ELo = Pl + 65536;
    float* ELl = ELo + 65536;
    f16* Kh = (f16*)(ELl + 65536);
    float* part = (float*)(Kh + 65536);
    float* part2 = part + 16 * 65536;

    // ---------- P0: recon + normalize ----------
    {
        if (t < 64) {
            float4 vz = z4[(size_t)b * 64 + t];
            float sz = vz.x * vz.x + vz.y * vz.y + vz.z * vz.z + vz.w * vz.w;
            sz = wave_red_sum(sz);
            float rnz = 1.f / sqrtf(fmaxf(sz, 1e-8f));
            f16x4 h;
            h[0] = (f16)(vz.x * rnz); h[1] = (f16)(vz.y * rnz);
            h[2] = (f16)(vz.z * rnz); h[3] = (f16)(vz.w * rnz);
            *(f16x4*)&zh[(size_t)b * 256 + t * 4] = h;
        }
        size_t ro = (size_t)b * 1024;
        float4 v0 = xo4[ro + t], v1 = xo4[ro + t + 512];
        float4 r0 = xr4[ro + t], r1 = xr4[ro + t + 512];
        float sq = v0.x * v0.x + v0.y * v0.y + v0.z * v0.z + v0.w * v0.w
                 + v1.x * v1.x + v1.y * v1.y + v1.z * v1.z + v1.w * v1.w;
        float d0 = r0.x - v0.x, d1 = r0.y - v0.y, d2 = r0.z - v0.z, d3 = r0.w - v0.w;
        float e0 = r1.x - v1.x, e1 = r1.y - v1.y, e2 = r1.z - v1.z, e3 = r1.w - v1.w;
        float rs = d0 * d0 + d1 * d1 + d2 * d2 + d3 * d3
                 + e0 * e0 + e1 * e1 + e2 * e2 + e3 * e3;
        float wq = wave_red_sum(sq), wr = wave_red_sum(rs);
        if (lane == 0) { sm.r.a[wv] = wq; sm.r.b[wv] = wr; }
        __syncthreads();
        float tq = 0.f, tr = 0.f;
        #pragma unroll
        for (int i = 0; i < 8; i++) { tq += sm.r.a[i]; tr += sm.r.b[i]; }
        if (t == 0) atomicAdd(acc + 3, tr);
        float rn = 1.f / sqrtf(fmaxf(tq, 1e-8f));
        f16x4 h0, h1;
        h0[0] = (f16)(v0.x * rn); h0[1] = (f16)(v0.y * rn);
        h0[2] = (f16)(v0.z * rn); h0[3] = (f16)(v0.w * rn);
        h1[0] = (f16)(v1.x * rn); h1[1] = (f16)(v1.y * rn);
        h1[2] = (f16)(v1.z * rn); h1[3] = (f16)(v1.w * rn);
        *(f16x4*)&xh[(size_t)b * 4096 + t * 4] = h0;
        *(f16x4*)&xh[(size_t)b * 4096 + 2048 + t * 4] = h1;
    }
    grid.sync();

    // ---------- P1: Gram GEMMs ----------
    {
        int tile = b >> 4, slab = b & 15;
        gemm_unit((const uint4*)xh, 512, (tile >> 2) * 64, (tile & 3) * 64,
                  slab * 32, part + (size_t)slab * 65536, sm, t);
        if (b >= 240) {
            int tl = b - 240;
            gemm_unit((const uint4*)zh, 32, (tl >> 2) * 64, (tl & 3) * 64, 0, part2, sm, t);
        }
    }
    grid.sync();

    // ---------- P2: Do + histogram ----------
    if (t < 256) {
        int e = b * 256 + t;
        float s = 0.f;
        for (int sl = 0; sl < 16; sl++) s += part[(size_t)sl * 65536 + e];
        float dv = fmaxf(1.f - s, 0.f);
        Do[e] = dv;
        atomicAdd(&hist[med_bin(dv)], 1);
    }
    grid.sync();

    // ---------- P3: block0 median || blocks 1..255 prep-a ----------
    if (b == 0) {
        median_phase(Do, hist, acc, sm, t);
    } else {
        prep_a_row(b - 1, t, sm, part2, Do, lsl, Pl, ELl, Kh);
        if (b == 255) prep_a_row(255, t, sm, part2, Do, lsl, Pl, ELl, Kh);
    }
    grid.sync();

    // ---------- P4: prep-b ----------
    prep_b_row(b, t, sm, Do, acc, Po, ELo);
}

// ================= Sinkhorn: 256 blocks x 512 thr, P=3 problems/block =================
// R6-proven register shape: 8 waves, 2 column-subtiles/wave, K frag = 16 uint4 =
// 64 VGPRs pinned (this shape compiled without spill at 95.6 us; the 128-VGPR
// variant in the fused kernel spilled to scratch -> 316 us).
// Epilogue redistributed: 768 (p,c) values over 512 threads (<=2 each, <=4 trans).
__global__ __launch_bounds__(512, 2) void k_sink(const float* __restrict__ Po,
                                                 const float* __restrict__ Pl,
                                                 const float* __restrict__ ELo,
                                                 const float* __restrict__ ELl,
                                                 const uint4* __restrict__ Kq,
                                                 float* __restrict__ acc) {
    __shared__ __align__(16) f16 U[4 * 272];      // rows 0..2 live, row 3 = dummy 1.0
    __shared__ __align__(16) float ZP[256][4];    // [col][p]  (p=3 junk)
    __shared__ float CW[8], CWb[4];
    int t = threadIdx.x;
    int lane = t & 63, wv = t >> 6, m16 = lane & 15, quad = lane >> 4;
    int b = blockIdx.x;

    // K fragments: wave wv owns cols [32wv, 32wv+32) as two 16-col subtiles
    uint4 bf0[8], bf1[8];
    int cA = 32 * wv + m16, cB = cA + 16;
    #pragma unroll
    for (int kc = 0; kc < 8; kc++) {
        bf0[kc] = Kq[(kc * 4 + quad) * 256 + cA];
        bf1[kc] = Kq[(kc * 4 + quad) * 256 + cB];
    }
    #pragma unroll
    for (int kc = 0; kc < 8; kc++) { PIN_U4(bf0[kc]); PIN_U4(bf1[kc]); }

    // epilogue values: valA = (pA = t>>8, cAv = t&255) for all t;
    //                  valB = (p=2,  cBv = t) for t<256
    int pA = t >> 8, cAv = t & 255;
    int rA = b * 3 + pA, sA = rA >> 8, iA = rA & 255;
    float elaA = ((sA == 1 ? ELl : ELo) + iA * 256)[cAv] + EPS * KSCALE_LN;
    float elbA = ((sA == 2 ? ELo : ELl) + iA * 256)[cAv] + EPS * KSCALE_LN;
    const float* paA = (sA == 1 ? Pl : Po) + iA * 256;
    const float* pbA = (sA == 2 ? Po : Pl) + iA * 256;
    int rB = b * 3 + 2, sB = rB >> 8, iB = rB & 255;
    float elaB = 0.f, elbB = 0.f;
    const float* paB = Po; const float* pbB = Po;
    if (t < 256) {
        elaB = ((sB == 1 ? ELl : ELo) + iB * 256)[t] + EPS * KSCALE_LN;
        elbB = ((sB == 2 ? ELo : ELl) + iB * 256)[t] + EPS * KSCALE_LN;
        paB = (sB == 1 ? Pl : Po) + iB * 256;
        pbB = (sB == 2 ? Po : Pl) + iB * 256;
    }

    // init U rows 0..3 = 1.0 (row 3 stays 1.0 forever: finite dummy)
    if (t < 136)
        *(uint4*)&U[t * 8] = make_uint4(0x3C003C00u, 0x3C003C00u, 0x3C003C00u, 0x3C003C00u);
    __syncthreads();

    float fvA = 0.f, gvA = 0.f, fvB = 0.f, gvB = 0.f;
    for (int it = 0; it < 2 * SINK_ITERS; it++) {
        // phase A: Z[3][256] = U x K via MFMA (all 8 waves)
        f32x4 acc0 = {0.f, 0.f, 0.f, 0.f}, acc1 = {0.f, 0.f, 0.f, 0.f};
        #pragma unroll
        for (int kc = 0; kc < 8; kc++) {
            f16x8 a = *(const f16x8*)&U[(m16 & 3) * 272 + kc * 32 + quad * 8];
            acc0 = __builtin_amdgcn_mfma_f32_16x16x32_f16(a, __builtin_bit_cast(f16x8, bf0[kc]), acc0, 0, 0, 0);
            acc1 = __builtin_amdgcn_mfma_f32_16x16x32_f16(a, __builtin_bit_cast(f16x8, bf1[kc]), acc1, 0, 0, 0);
        }
        if (quad == 0) {   // C/D: col=lane&15, row(p)=reg
            *(f32x4*)&ZP[cA][0] = acc0;
            *(f32x4*)&ZP[cB][0] = acc1;
        }
        __syncthreads();
        // phase B: dual update, distributed
        {
            bool fstep = (it & 1);
            float z0 = ZP[cAv][pA];
            float e0 = fstep ? elaA : elbA;
            float d0 = e0 - EPS * __logf(z0);
            if (fstep) fvA = d0; else gvA = d0;
            U[pA * 272 + cAv] = (f16)__expf(d0);
            if (t < 256) {
                float z1 = ZP[t][2];
                float e1 = fstep ? elaB : elbB;
                float d1 = e1 - EPS * __logf(z1);
                if (fstep) fvB = d1; else gvB = d1;
                U[2 * 272 + t] = (f16)__expf(d1);
            }
        }
        __syncthreads();
    }

    // cost epilogue
    float csA = paA[cAv] * fvA + pbA[cAv] * gvA;
    float csB = (t < 256) ? (paB[t] * fvB + pbB[t] * gvB) : 0.f;
    float vA = wave_red_sum(csA);
    float vB = wave_red_sum(csB);
    if (lane == 0) { CW[wv] = vA; if (wv < 4) CWb[wv] = vB; }
    __syncthreads();
    if (t < 3) {
        float s;
        if (t == 0) s = CW[0] + CW[1] + CW[2] + CW[3];
        else if (t == 1) s = CW[4] + CW[5] + CW[6] + CW[7];
        else s = CWb[0] + CWb[1] + CWb[2] + CWb[3];
        atomicAdd(&acc[(b * 3 + t) >> 8], s);
    }
}

// ---------------- finalize ----------------
__global__ void k_final(const float* __restrict__ acc, const float* __restrict__ lvr_p,
                        const float* __restrict__ lvt_p, float* __restrict__ out) {
    float recon = acc[3] * (1.f / (256.f * 4096.f));
    float ot0 = acc[0] * (1.f / 256.f);
    float ot1 = acc[1] * (1.f / 256.f);
    float ot2 = acc[2] * (1.f / 256.f);
    float topo = ot0 - 0.5f * ot1 - 0.5f * ot2;
    topo = topo > 0.f ? topo : 0.f;  // * TOPO_MULT (=1)
    float a = lvr_p[0], c = lvt_p[0];
    out[0] = 0.5f * __expf(-a) * recon + 0.5f * a +
             0.5f * __expf(-c) * topo + 0.5f * c;
    out[1] = recon;
    out[2] = topo;
}

extern "C" void kernel_launch(void* const* d_in, const int* in_sizes, int n_in,
                              void* d_out, int out_size, void* d_ws, size_t ws_size,
                              hipStream_t stream) {
    const float4* xo4 = (const float4*)d_in[0];
    const float4* xr4 = (const float4*)d_in[1];
    const float4* z4  = (const float4*)d_in[2];
    const float* lsl = (const float*)d_in[3];
    const float* lvr = (const float*)d_in[4];
    const float* lvt = (const float*)d_in[5];
    float* out = (float*)d_out;
    float* ws = (float*)d_ws;

    // ws layout (floats) — must match k_pre_coop
    float* acc = ws;
    f16* xh = (f16*)(ws + 64 + 8192);
    f16* zh = xh + 1048576;
    float* Do = (float*)(zh + 65536);
    float* Po = Do + 65536;
    float* Pl = Po + 65536;
    float* ELo = Pl + 65536;
    float* ELl = ELo + 65536;
    f16* Kh = (f16*)(ELl + 65536);

    hipMemsetAsync(ws, 0, (64 + 8192) * sizeof(float), stream);

    void* kargs[] = {(void*)&xo4, (void*)&xr4, (void*)&z4, (void*)&lsl, (void*)&ws};
    hipLaunchCooperativeKernel((void*)k_pre_coop, dim3(256), dim3(512), kargs, 0, stream);

    k_sink<<<256, 512, 0, stream>>>(Po, Pl, ELo, ELl, (const uint4*)Kh, acc);
    k_final<<<1, 1, 0, stream>>>(acc, lvr, lvt, out);
}